// Round 6
// baseline (306.292 us; speedup 1.0000x reference)
//
#include <hip/hip_runtime.h>
#include <hip/hip_fp16.h>

// SoftPerspectiveShader: barycentric texture sampling + softmax RGB blend.
// N=4, H=W=512, K=8, F=200000.
//
// R1-R6 summary: weight-gated gather, nt streams, fp16 4MB face table.
// 61.5 us, 2.6 TB/s, FETCH 140 MB (near-minimal). Structure-invariant
// perf (occ/ILP/VGPR/nt all neutral); R6 gain == bytes removed / 2.6 TB/s
// => machine acts as a fixed ~2.6 TB/s pipe for this fused access mix.
// R7 (this round): SPLIT stream phase from gather phase to (a) let the
// pure-coalesced phase run at full streaming BW and (b) measure each
// phase's BW separately (decisive between "scatter poisons the pipe"
// and "systemic 2.6 TB/s cap").
//   P1 stream_kernel: coalesced-only. Computes denom/delta/keep/winner
//     EXACTLY (no texels needed), writes 16 B/px record INTO out buffer.
//     Rare extra gate-passers (~0.9%/px) -> atomic task list in ws.
//   P2a gather_kernel: record (L2-hot) + winner bary + fp16 color gather,
//     writes final pixel.
//   P2b extras_kernel: ~9K tasks, atomicAdd second-passer contributions.

#define KFRAG 8
#define TASK_CAP 65536

typedef int   ivec4 __attribute__((ext_vector_type(4)));
typedef float fvec4 __attribute__((ext_vector_type(4)));
typedef unsigned int uvec4 __attribute__((ext_vector_type(4)));
typedef float fvec4a __attribute__((ext_vector_type(4), aligned(4)));
typedef unsigned int uvec4a __attribute__((ext_vector_type(4), aligned(4)));

constexpr float SIGMA_INV = 1.0f / 1e-4f;
constexpr float GAMMA_INV = 1.0f / 1e-4f;
constexpr float EPS    = 1e-10f;
constexpr float ZFAR   = 100.0f;
constexpr float ZSCALE = 1.0f / 99.0f;
constexpr float ZCUT   = -1.2e-3f;     // exp(ZCUT*1e4) < 1e-5: negligible
constexpr unsigned FID_SENTINEL = 0x3FFFFu; // > max fid (199999)

__device__ __forceinline__ float h2f(unsigned short u) {
    __half h; __builtin_memcpy(&h, &u, 2); return __half2float(h);
}

// ---- prepass: f32 [F][9] -> fp16 [F][10] table; zero the task counter ----
__global__ __launch_bounds__(256) void repack_kernel(
    const float* __restrict__ fc, __half* __restrict__ ht,
    unsigned int* __restrict__ cnt, int F9)
{
    int i = blockIdx.x * blockDim.x + threadIdx.x;
    if (i == 0) *cnt = 0u;
    if (i >= F9) return;
    int f = i / 9;
    int c = i - f * 9;
    ht[(size_t)f * 10 + c] = __float2half(fc[i]);
}

// ---- phase 1: pure coalesced streaming, full softmax algebra ----
__global__ __launch_bounds__(256) void stream_kernel(
    const int*   __restrict__ p2f,    // [NP, 8]
    const float* __restrict__ zbuf,   // [NP, 8]
    const float* __restrict__ dists,  // [NP, 8]
    uvec4*       __restrict__ recs,   // [NP] (aliases out buffer)
    unsigned int* __restrict__ cnt,
    uvec4*       __restrict__ tasks,  // [TASK_CAP]
    int NP)
{
    int p = blockIdx.x * blockDim.x + threadIdx.x;
    if (p >= NP) return;

    const ivec4* p2f4 = (const ivec4*)p2f + (size_t)p * 2;
    ivec4 f0 = __builtin_nontemporal_load(p2f4 + 0);
    ivec4 f1 = __builtin_nontemporal_load(p2f4 + 1);
    const fvec4* zb4 = (const fvec4*)zbuf + (size_t)p * 2;
    fvec4 z0 = __builtin_nontemporal_load(zb4 + 0);
    fvec4 z1 = __builtin_nontemporal_load(zb4 + 1);
    const fvec4* dd4 = (const fvec4*)dists + (size_t)p * 2;
    fvec4 d0 = __builtin_nontemporal_load(dd4 + 0);
    fvec4 d1 = __builtin_nontemporal_load(dd4 + 1);

    int   fid[KFRAG] = {f0.x, f0.y, f0.z, f0.w, f1.x, f1.y, f1.z, f1.w};
    float zb_[KFRAG] = {z0.x, z0.y, z0.z, z0.w, z1.x, z1.y, z1.z, z1.w};
    float dd_[KFRAG] = {d0.x, d0.y, d0.z, d0.w, d1.x, d1.y, d1.z, d1.w};

    // winner = first valid (zbuf sorted ascending -> max zinv among valid)
    int fidw = -1, kw = 0;
#pragma unroll
    for (int k = KFRAG - 1; k >= 0; --k)
        if (fid[k] >= 0) { fidw = fid[k]; kw = k; }

    float zinv[KFRAG], prob[KFRAG];
    float zmax = EPS;
    float keep = 1.0f;
#pragma unroll
    for (int k = 0; k < KFRAG; ++k) {
        bool v = (fid[k] >= 0);
        zinv[k] = v ? ((ZFAR - zb_[k]) * ZSCALE) : 0.0f;
        zmax = fmaxf(zmax, zinv[k]);
        prob[k] = v ? (1.0f / (1.0f + __expf(dd_[k] * SIGMA_INV))) : 0.0f;
        keep *= (1.0f - prob[k]);
    }

    // exact denom over ALL fragments (no texel needed)
    float w[KFRAG], wsum = 0.0f;
#pragma unroll
    for (int k = 0; k < KFRAG; ++k) {
        w[k] = prob[k] * __expf((zinv[k] - zmax) * GAMMA_INV);
        wsum += w[k];
    }
    float delta = fmaxf(__expf((EPS - zmax) * GAMMA_INV), EPS);
    float denom = delta + wsum;
    float inv = 1.0f / denom;

    float wwin = 0.0f; // w[kw] via static cascade (no dynamic indexing)
#pragma unroll
    for (int k = KFRAG - 1; k >= 0; --k)
        if (fid[k] >= 0) wwin = w[k];

    // rare extra gate-passers -> task list (only k > kw can be valid)
#pragma unroll
    for (int k = 0; k < KFRAG; ++k) {
        if ((fid[k] >= 0) && (k != kw) && (zinv[k] - zmax > ZCUT)) {
            unsigned idx = atomicAdd(cnt, 1u);
            if (idx < TASK_CAP) {
                uvec4 t;
                t.x = (unsigned)p;
                t.y = ((unsigned)k << 18) | (unsigned)fid[k];
                t.z = __float_as_uint(w[k] * inv);
                t.w = 0u;
                tasks[idx] = t;
            }
        }
    }

    uvec4 rec;
    rec.x = (fidw >= 0) ? (((unsigned)kw << 18) | (unsigned)fidw) : FID_SENTINEL;
    rec.y = __float_as_uint(wwin * inv);
    rec.z = __float_as_uint(delta * inv);
    rec.w = __float_as_uint(keep);
    recs[p] = rec; // regular store: consumed by next dispatch
}

// ---- phase 2a: winner gather + blend (records are L2-hot) ----
__global__ __launch_bounds__(256) void gather_kernel(
    const float*  __restrict__ bary, // [NP, 8, 3]
    const __half* __restrict__ ht,   // [F, 10]
    float*        out,               // [NP, 4]; rec read then overwritten
    int NP)
{
    int p = blockIdx.x * blockDim.x + threadIdx.x;
    if (p >= NP) return;

    uvec4 rc = *((const uvec4*)out + p);
    unsigned packed = rc.x;
    float wm   = __uint_as_float(rc.y);
    float base = __uint_as_float(rc.z);
    float keep = __uint_as_float(rc.w);

    float r = base, g = base, b = base;
    if (packed != FID_SENTINEL) {
        int fidw = (int)(packed & 0x3FFFFu);
        int kw   = (int)((packed >> 18) & 7u);

        // 12 B bary as one dwordx4; clamp the single end-overrun case
        size_t boff = (size_t)p * 24 + kw * 3;
        bool cl = (boff + 4) > (size_t)NP * 24;
        const float* bb = bary + (boff - (cl ? 1 : 0));
        fvec4a q = *(const fvec4a*)bb;
        float b0 = cl ? q.y : q.x;
        float b1 = cl ? q.z : q.y;
        float b2 = cl ? q.w : q.z;

        const __half* hp = ht + (size_t)fidw * 10; // 20 B/face
        uvec4a hq = *(const uvec4a*)hp;            // h0..h7
        unsigned short h8 = ((const unsigned short*)hp)[8];
        float c0 = h2f((unsigned short)(hq.x & 0xffff));
        float c1 = h2f((unsigned short)(hq.x >> 16));
        float c2 = h2f((unsigned short)(hq.y & 0xffff));
        float c3 = h2f((unsigned short)(hq.y >> 16));
        float c4 = h2f((unsigned short)(hq.z & 0xffff));
        float c5 = h2f((unsigned short)(hq.z >> 16));
        float c6 = h2f((unsigned short)(hq.w & 0xffff));
        float c7 = h2f((unsigned short)(hq.w >> 16));
        float c8 = h2f(h8);

        float tr = fmaf(b0, c0, fmaf(b1, c3, b2 * c6));
        float tg = fmaf(b0, c1, fmaf(b1, c4, b2 * c7));
        float tb = fmaf(b0, c2, fmaf(b1, c5, b2 * c8));
        r = fmaf(wm, tr, base);
        g = fmaf(wm, tg, base);
        b = fmaf(wm, tb, base);
    }

    fvec4 o; o.x = r; o.y = g; o.z = b; o.w = keep;
    __builtin_nontemporal_store(o, (fvec4*)out + p);
}

// ---- phase 2b: rare second-passer contributions (after 2a) ----
__global__ __launch_bounds__(256) void extras_kernel(
    const float*  __restrict__ bary,
    const __half* __restrict__ ht,
    const unsigned int* __restrict__ cnt,
    const uvec4*  __restrict__ tasks,
    float* out, int NP)
{
    int t = blockIdx.x * blockDim.x + threadIdx.x;
    unsigned n = *cnt;
    if (n > TASK_CAP) n = TASK_CAP;
    if ((unsigned)t >= n) return;

    uvec4 tk = tasks[t];
    int p = (int)tk.x;
    int fid = (int)(tk.y & 0x3FFFFu);
    int k   = (int)((tk.y >> 18) & 7u);
    float w = __uint_as_float(tk.z);

    size_t boff = (size_t)p * 24 + k * 3;
    bool cl = (boff + 4) > (size_t)NP * 24;
    const float* bb = bary + (boff - (cl ? 1 : 0));
    fvec4a q = *(const fvec4a*)bb;
    float b0 = cl ? q.y : q.x;
    float b1 = cl ? q.z : q.y;
    float b2 = cl ? q.w : q.z;

    const __half* hp = ht + (size_t)fid * 10;
    uvec4a hq = *(const uvec4a*)hp;
    unsigned short h8 = ((const unsigned short*)hp)[8];
    float c0 = h2f((unsigned short)(hq.x & 0xffff));
    float c1 = h2f((unsigned short)(hq.x >> 16));
    float c2 = h2f((unsigned short)(hq.y & 0xffff));
    float c3 = h2f((unsigned short)(hq.y >> 16));
    float c4 = h2f((unsigned short)(hq.z & 0xffff));
    float c5 = h2f((unsigned short)(hq.z >> 16));
    float c6 = h2f((unsigned short)(hq.w & 0xffff));
    float c7 = h2f((unsigned short)(hq.w >> 16));
    float c8 = h2f(h8);

    float tr = fmaf(b0, c0, fmaf(b1, c3, b2 * c6));
    float tg = fmaf(b0, c1, fmaf(b1, c4, b2 * c7));
    float tb = fmaf(b0, c2, fmaf(b1, c5, b2 * c8));

    atomicAdd(out + (size_t)p * 4 + 0, w * tr);
    atomicAdd(out + (size_t)p * 4 + 1, w * tg);
    atomicAdd(out + (size_t)p * 4 + 2, w * tb);
}

// ---- fallback: single-kernel f32 path (if ws too small) ----
__global__ __launch_bounds__(256) void fused_kernel(
    const int* __restrict__ p2f, const float* __restrict__ bary,
    const float* __restrict__ zbuf, const float* __restrict__ dists,
    const float* __restrict__ face_colors, float* __restrict__ out, int NP)
{
    int p = blockIdx.x * blockDim.x + threadIdx.x;
    if (p >= NP) return;
    const ivec4* p2f4 = (const ivec4*)p2f + (size_t)p * 2;
    ivec4 f0 = p2f4[0], f1 = p2f4[1];
    const fvec4* zb4 = (const fvec4*)zbuf + (size_t)p * 2;
    fvec4 z0 = zb4[0], z1 = zb4[1];
    const fvec4* dd4 = (const fvec4*)dists + (size_t)p * 2;
    fvec4 d0 = dd4[0], d1 = dd4[1];
    int   fid[KFRAG] = {f0.x, f0.y, f0.z, f0.w, f1.x, f1.y, f1.z, f1.w};
    float zb_[KFRAG] = {z0.x, z0.y, z0.z, z0.w, z1.x, z1.y, z1.z, z1.w};
    float dd_[KFRAG] = {d0.x, d0.y, d0.z, d0.w, d1.x, d1.y, d1.z, d1.w};
    float zinv[KFRAG], prob[KFRAG], zmax = EPS, keep = 1.0f;
#pragma unroll
    for (int k = 0; k < KFRAG; ++k) {
        bool v = (fid[k] >= 0);
        zinv[k] = v ? ((ZFAR - zb_[k]) * ZSCALE) : 0.0f;
        zmax = fmaxf(zmax, zinv[k]);
        prob[k] = v ? (1.0f / (1.0f + __expf(dd_[k] * SIGMA_INV))) : 0.0f;
        keep *= (1.0f - prob[k]);
    }
    float delta = fmaxf(__expf((EPS - zmax) * GAMMA_INV), EPS);
    float denom = delta, r = 0.f, g = 0.f, b = 0.f;
#pragma unroll
    for (int k = 0; k < KFRAG; ++k) {
        float w = prob[k] * __expf((zinv[k] - zmax) * GAMMA_INV);
        denom += w;
        if ((fid[k] >= 0) && (zinv[k] - zmax > ZCUT)) {
            const float* bp = bary + (size_t)p * 24 + k * 3;
            float c0 = bp[0], c1 = bp[1], c2 = bp[2];
            const float* fc = face_colors + (size_t)fid[k] * 9;
            float e[9];
            __builtin_memcpy(e, fc, 36);
            r = fmaf(w, fmaf(c0, e[0], fmaf(c1, e[3], c2 * e[6])), r);
            g = fmaf(w, fmaf(c0, e[1], fmaf(c1, e[4], c2 * e[7])), g);
            b = fmaf(w, fmaf(c0, e[2], fmaf(c1, e[5], c2 * e[8])), b);
        }
    }
    float inv = 1.0f / denom;
    fvec4 o;
    o.x = (r + delta) * inv; o.y = (g + delta) * inv; o.z = (b + delta) * inv;
    o.w = keep;
    *((fvec4*)out + p) = o;
}

extern "C" void kernel_launch(void* const* d_in, const int* in_sizes, int n_in,
                              void* d_out, int out_size, void* d_ws, size_t ws_size,
                              hipStream_t stream) {
    const int*   p2f         = (const int*)d_in[0];
    const float* bary        = (const float*)d_in[1];
    const float* zbuf        = (const float*)d_in[2];
    const float* dists       = (const float*)d_in[3];
    const float* face_colors = (const float*)d_in[4];
    float* out = (float*)d_out;

    int NP = in_sizes[0] / KFRAG; // N*H*W pixels
    int F9 = in_sizes[4];         // F * 9
    int F  = F9 / 9;

    size_t tabBytes = (size_t)F * 10 * sizeof(__half);      // 4,000,000
    size_t cntOff   = (tabBytes + 63) & ~(size_t)63;        // 64-aligned
    size_t taskOff  = cntOff + 64;
    size_t need     = taskOff + (size_t)TASK_CAP * 16;      // ~5.05 MB

    int block = 256;
    int grid  = (NP + block - 1) / block;

    if (d_ws && ws_size >= need) {
        char* ws = (char*)d_ws;
        __half* ht = (__half*)ws;
        unsigned int* cnt = (unsigned int*)(ws + cntOff);
        uvec4* tasks = (uvec4*)(ws + taskOff);

        int rgrid = (F9 + block - 1) / block;
        repack_kernel<<<rgrid, block, 0, stream>>>(face_colors, ht, cnt, F9);
        stream_kernel<<<grid, block, 0, stream>>>(
            p2f, zbuf, dists, (uvec4*)out, cnt, tasks, NP);
        gather_kernel<<<grid, block, 0, stream>>>(bary, ht, out, NP);
        extras_kernel<<<TASK_CAP / 256, block, 0, stream>>>(
            bary, ht, cnt, tasks, out, NP);
    } else {
        fused_kernel<<<grid, block, 0, stream>>>(
            p2f, bary, zbuf, dists, face_colors, out, NP);
    }
}

// Round 8
// 230.073 us; speedup vs baseline: 1.3313x; 1.3313x over previous
//
#include <hip/hip_runtime.h>
#include <hip/hip_fp16.h>

// SoftPerspectiveShader: barycentric texture sampling + softmax RGB blend.
// N=4, H=W=512, K=8, F=200000.
//
// R1-R6: weight-gated gather, nt streams, fp16 4MB face table -> 61.5 us,
//   ~2.55 TB/s effective regardless of structure (occ/ILP/VGPR/nt neutral).
// R7: split stream/gather probe POISONED by ~11K same-address atomicAdds
//   (single counter, return-value dep) -> stream phase 100 us. Lesson:
//   Guideline 12. The decisive stream-BW number was never measured.
// R8: atomic-free split (this round = resubmit; R7 bench was an infra
//   failure, no data).
//   P1 stream_kernel: coalesced-only; computes denom/delta/keep EXACTLY;
//     encodes winner + ONE extra inline in a 16 B record (weights as 2xf16);
//     >=2 extras (~120 px) -> fallback sentinel.
//   P2 gather_kernel: record (hot) + winner bary + fp16 table (+ rare
//     extra via p2f[8p+ke]); fallback pixels recomputed exactly in f32.
//   Decision rule: stream at >=4 TB/s -> divergence was the cap (optimize
//   gather next); stream at ~2 TB/s -> systemic cap, R6 was ~roofline.

#define KFRAG 8

typedef int   ivec4 __attribute__((ext_vector_type(4)));
typedef float fvec4 __attribute__((ext_vector_type(4)));
typedef unsigned int uvec4 __attribute__((ext_vector_type(4)));
typedef float fvec4a __attribute__((ext_vector_type(4), aligned(4)));
typedef unsigned int uvec4a __attribute__((ext_vector_type(4), aligned(4)));

constexpr float SIGMA_INV = 1.0f / 1e-4f;
constexpr float GAMMA_INV = 1.0f / 1e-4f;
constexpr float EPS    = 1e-10f;
constexpr float ZFAR   = 100.0f;
constexpr float ZSCALE = 1.0f / 99.0f;
constexpr float ZCUT   = -1.2e-3f;      // exp(ZCUT*1e4) < 1e-5: negligible
constexpr unsigned SENT_BG = 0x3FFFFu;  // no valid fragment
constexpr unsigned SENT_FB = 0x3FFFEu;  // >=2 extras: full f32 recompute

__device__ __forceinline__ float h2f(unsigned short u) {
    __half h; __builtin_memcpy(&h, &u, 2); return __half2float(h);
}

// ---- prepass: f32 [F][9] -> fp16 [F][10] table ----
__global__ __launch_bounds__(256) void repack_kernel(
    const float* __restrict__ fc, __half* __restrict__ ht, int F9)
{
    int i = blockIdx.x * blockDim.x + threadIdx.x;
    if (i >= F9) return;
    int f = i / 9;
    int c = i - f * 9;
    ht[(size_t)f * 10 + c] = __float2half(fc[i]);
}

// ---- exact per-pixel f32 path (fallback + no-ws kernel) ----
__device__ void full_pixel(int p, const int* __restrict__ p2f,
                           const float* __restrict__ bary,
                           const float* __restrict__ zbuf,
                           const float* __restrict__ dists,
                           const float* __restrict__ fc32,
                           float* __restrict__ out)
{
    int fid[KFRAG]; float zb_[KFRAG], dd_[KFRAG];
#pragma unroll
    for (int k = 0; k < KFRAG; ++k) {
        fid[k] = p2f[(size_t)p * 8 + k];
        zb_[k] = zbuf[(size_t)p * 8 + k];
        dd_[k] = dists[(size_t)p * 8 + k];
    }
    float zinv[KFRAG], prob[KFRAG], zmax = EPS, keep = 1.0f;
#pragma unroll
    for (int k = 0; k < KFRAG; ++k) {
        bool v = (fid[k] >= 0);
        zinv[k] = v ? ((ZFAR - zb_[k]) * ZSCALE) : 0.0f;
        zmax = fmaxf(zmax, zinv[k]);
        prob[k] = v ? (1.0f / (1.0f + __expf(dd_[k] * SIGMA_INV))) : 0.0f;
        keep *= (1.0f - prob[k]);
    }
    float delta = fmaxf(__expf((EPS - zmax) * GAMMA_INV), EPS);
    float denom = delta, r = 0.f, g = 0.f, b = 0.f;
#pragma unroll
    for (int k = 0; k < KFRAG; ++k) {
        float w = prob[k] * __expf((zinv[k] - zmax) * GAMMA_INV);
        denom += w;
        if ((fid[k] >= 0) && (zinv[k] - zmax > ZCUT)) {
            const float* bp = bary + (size_t)p * 24 + k * 3;
            float c0 = bp[0], c1 = bp[1], c2 = bp[2];
            const float* fc = fc32 + (size_t)fid[k] * 9;
            float e[9];
            __builtin_memcpy(e, fc, 36);
            r = fmaf(w, fmaf(c0, e[0], fmaf(c1, e[3], c2 * e[6])), r);
            g = fmaf(w, fmaf(c0, e[1], fmaf(c1, e[4], c2 * e[7])), g);
            b = fmaf(w, fmaf(c0, e[2], fmaf(c1, e[5], c2 * e[8])), b);
        }
    }
    float inv = 1.0f / denom;
    fvec4 o;
    o.x = (r + delta) * inv; o.y = (g + delta) * inv; o.z = (b + delta) * inv;
    o.w = keep;
    *((fvec4*)out + p) = o;
}

// ---- phase 1: pure coalesced streaming; NO atomics, NO divergent loads ----
__global__ __launch_bounds__(256) void stream_kernel(
    const int*   __restrict__ p2f,    // [NP, 8]
    const float* __restrict__ zbuf,   // [NP, 8]
    const float* __restrict__ dists,  // [NP, 8]
    uvec4*       __restrict__ recs,   // [NP] (aliases out buffer)
    int NP)
{
    int p = blockIdx.x * blockDim.x + threadIdx.x;
    if (p >= NP) return;

    const ivec4* p2f4 = (const ivec4*)p2f + (size_t)p * 2;
    ivec4 f0 = __builtin_nontemporal_load(p2f4 + 0);
    ivec4 f1 = __builtin_nontemporal_load(p2f4 + 1);
    const fvec4* zb4 = (const fvec4*)zbuf + (size_t)p * 2;
    fvec4 z0 = __builtin_nontemporal_load(zb4 + 0);
    fvec4 z1 = __builtin_nontemporal_load(zb4 + 1);
    const fvec4* dd4 = (const fvec4*)dists + (size_t)p * 2;
    fvec4 d0 = __builtin_nontemporal_load(dd4 + 0);
    fvec4 d1 = __builtin_nontemporal_load(dd4 + 1);

    int   fid[KFRAG] = {f0.x, f0.y, f0.z, f0.w, f1.x, f1.y, f1.z, f1.w};
    float zb_[KFRAG] = {z0.x, z0.y, z0.z, z0.w, z1.x, z1.y, z1.z, z1.w};
    float dd_[KFRAG] = {d0.x, d0.y, d0.z, d0.w, d1.x, d1.y, d1.z, d1.w};

    // winner = first valid (zbuf sorted ascending -> max zinv among valid)
    int fidw = -1, kw = 0;
#pragma unroll
    for (int k = KFRAG - 1; k >= 0; --k)
        if (fid[k] >= 0) { fidw = fid[k]; kw = k; }

    float zinv[KFRAG], prob[KFRAG];
    float zmax = EPS, keep = 1.0f;
#pragma unroll
    for (int k = 0; k < KFRAG; ++k) {
        bool v = (fid[k] >= 0);
        zinv[k] = v ? ((ZFAR - zb_[k]) * ZSCALE) : 0.0f;
        zmax = fmaxf(zmax, zinv[k]);
        prob[k] = v ? (1.0f / (1.0f + __expf(dd_[k] * SIGMA_INV))) : 0.0f;
        keep *= (1.0f - prob[k]);
    }

    // exact denom over ALL fragments (no texel needed)
    float w[KFRAG], wsum = 0.0f;
#pragma unroll
    for (int k = 0; k < KFRAG; ++k) {
        w[k] = prob[k] * __expf((zinv[k] - zmax) * GAMMA_INV);
        wsum += w[k];
    }
    float delta = fmaxf(__expf((EPS - zmax) * GAMMA_INV), EPS);
    float inv = 1.0f / (delta + wsum);

    float wwin = 0.0f; // w[kw] via static cascade
#pragma unroll
    for (int k = KFRAG - 1; k >= 0; --k)
        if (fid[k] >= 0) wwin = w[k];

    // extras: k != kw passing the gate. Encode first inline; >=2 -> fallback.
    int ke = 0, ne = 0; float we = 0.0f;
#pragma unroll
    for (int k = 0; k < KFRAG; ++k) {
        bool e = (fid[k] >= 0) && (k != kw) && (zinv[k] - zmax > ZCUT);
        if (e) {
            if (ne == 0) { ke = k; we = w[k] * inv; }
            ne++;
        }
    }

    unsigned px;
    if (fidw < 0)      px = SENT_BG;
    else if (ne >= 2)  px = SENT_FB;
    else px = (unsigned)fidw | ((unsigned)kw << 18) | ((unsigned)ke << 21);

    unsigned hw = (unsigned)__half_as_ushort(__float2half(wwin * inv));
    unsigned he = (unsigned)__half_as_ushort(__float2half(we));

    uvec4 rec;
    rec.x = px;
    rec.y = hw | (he << 16);
    rec.z = __float_as_uint(delta * inv);
    rec.w = __float_as_uint(keep);
    recs[p] = rec;
}

// ---- phase 2: winner (+rare extra) gather + blend ----
__global__ __launch_bounds__(256) void gather_kernel(
    const int*    __restrict__ p2f,
    const float*  __restrict__ bary,  // [NP, 8, 3]
    const float*  __restrict__ zbuf,
    const float*  __restrict__ dists,
    const float*  __restrict__ fc32,  // exact table for fallback
    const __half* __restrict__ ht,    // [F, 10]
    float*        out,                // [NP, 4]; rec read then overwritten
    int NP)
{
    int p = blockIdx.x * blockDim.x + threadIdx.x;
    if (p >= NP) return;

    uvec4 rc = *((const uvec4*)out + p);
    unsigned packed = rc.x;

    if (packed == SENT_FB) { // ~1e-4 of pixels: exact recompute
        full_pixel(p, p2f, bary, zbuf, dists, fc32, out);
        return;
    }

    float base = __uint_as_float(rc.z);
    float keep = __uint_as_float(rc.w);
    float r = base, g = base, b = base;

    if (packed != SENT_BG) {
        int fidw = (int)(packed & 0x3FFFFu);
        int kw   = (int)((packed >> 18) & 7u);
        int ke   = (int)((packed >> 21) & 7u);
        float wm = h2f((unsigned short)(rc.y & 0xffffu));

        // winner bary: 12 B as one dwordx4; clamp the single end-overrun case
        size_t boff = (size_t)p * 24 + kw * 3;
        bool cl = (boff + 4) > (size_t)NP * 24;
        const float* bb = bary + (boff - (cl ? 1 : 0));
        fvec4a q = *(const fvec4a*)bb;
        float b0 = cl ? q.y : q.x;
        float b1 = cl ? q.z : q.y;
        float b2 = cl ? q.w : q.z;

        const __half* hp = ht + (size_t)fidw * 10; // 20 B/face
        uvec4a hq = *(const uvec4a*)hp;
        unsigned short h8 = ((const unsigned short*)hp)[8];
        float c0 = h2f((unsigned short)(hq.x & 0xffff));
        float c1 = h2f((unsigned short)(hq.x >> 16));
        float c2 = h2f((unsigned short)(hq.y & 0xffff));
        float c3 = h2f((unsigned short)(hq.y >> 16));
        float c4 = h2f((unsigned short)(hq.z & 0xffff));
        float c5 = h2f((unsigned short)(hq.z >> 16));
        float c6 = h2f((unsigned short)(hq.w & 0xffff));
        float c7 = h2f((unsigned short)(hq.w >> 16));
        float c8 = h2f(h8);

        r = fmaf(wm, fmaf(b0, c0, fmaf(b1, c3, b2 * c6)), r);
        g = fmaf(wm, fmaf(b0, c1, fmaf(b1, c4, b2 * c7)), g);
        b = fmaf(wm, fmaf(b0, c2, fmaf(b1, c5, b2 * c8)), b);

        if (ke) { // ~1.1% of pixels: one extra gate-passer
            float wex = h2f((unsigned short)(rc.y >> 16));
            int fide = p2f[(size_t)p * 8 + ke]; // valid by construction
            const float* bp = bary + (size_t)p * 24 + ke * 3;
            float e0 = bp[0], e1 = bp[1], e2 = bp[2];
            const __half* hp2 = ht + (size_t)fide * 10;
            uvec4a h2 = *(const uvec4a*)hp2;
            unsigned short h28 = ((const unsigned short*)hp2)[8];
            float d0 = h2f((unsigned short)(h2.x & 0xffff));
            float d1 = h2f((unsigned short)(h2.x >> 16));
            float d2 = h2f((unsigned short)(h2.y & 0xffff));
            float d3 = h2f((unsigned short)(h2.y >> 16));
            float d4 = h2f((unsigned short)(h2.z & 0xffff));
            float d5 = h2f((unsigned short)(h2.z >> 16));
            float d6 = h2f((unsigned short)(h2.w & 0xffff));
            float d7 = h2f((unsigned short)(h2.w >> 16));
            float d8 = h2f(h28);
            r = fmaf(wex, fmaf(e0, d0, fmaf(e1, d3, e2 * d6)), r);
            g = fmaf(wex, fmaf(e0, d1, fmaf(e1, d4, e2 * d7)), g);
            b = fmaf(wex, fmaf(e0, d2, fmaf(e1, d5, e2 * d8)), b);
        }
    }

    fvec4 o; o.x = r; o.y = g; o.z = b; o.w = keep;
    __builtin_nontemporal_store(o, (fvec4*)out + p);
}

// ---- fallback: single fused f32 kernel (if ws too small) ----
__global__ __launch_bounds__(256) void fused_kernel(
    const int* __restrict__ p2f, const float* __restrict__ bary,
    const float* __restrict__ zbuf, const float* __restrict__ dists,
    const float* __restrict__ face_colors, float* __restrict__ out, int NP)
{
    int p = blockIdx.x * blockDim.x + threadIdx.x;
    if (p >= NP) return;
    full_pixel(p, p2f, bary, zbuf, dists, face_colors, out);
}

extern "C" void kernel_launch(void* const* d_in, const int* in_sizes, int n_in,
                              void* d_out, int out_size, void* d_ws, size_t ws_size,
                              hipStream_t stream) {
    const int*   p2f         = (const int*)d_in[0];
    const float* bary        = (const float*)d_in[1];
    const float* zbuf        = (const float*)d_in[2];
    const float* dists       = (const float*)d_in[3];
    const float* face_colors = (const float*)d_in[4];
    float* out = (float*)d_out;

    int NP = in_sizes[0] / KFRAG; // N*H*W pixels
    int F9 = in_sizes[4];         // F * 9
    int F  = F9 / 9;
    size_t need = (size_t)F * 10 * sizeof(__half); // 4.0 MB

    int block = 256;
    int grid  = (NP + block - 1) / block;

    if (d_ws && ws_size >= need) {
        __half* ht = (__half*)d_ws;
        int rgrid = (F9 + block - 1) / block;
        repack_kernel<<<rgrid, block, 0, stream>>>(face_colors, ht, F9);
        stream_kernel<<<grid, block, 0, stream>>>(
            p2f, zbuf, dists, (uvec4*)out, NP);
        gather_kernel<<<grid, block, 0, stream>>>(
            p2f, bary, zbuf, dists, face_colors, ht, out, NP);
    } else {
        fused_kernel<<<grid, block, 0, stream>>>(
            p2f, bary, zbuf, dists, face_colors, out, NP);
    }
}

// Round 9
// 220.578 us; speedup vs baseline: 1.3886x; 1.0430x over previous
//
#include <hip/hip_runtime.h>

// SoftPerspectiveShader: barycentric texture sampling + softmax RGB blend.
// N=4, H=W=512, K=8, F=200000.
//
// R1-R6: weight-gated gather + nt streams + fp16 table -> 61.5 us fused,
//   ~2.6 TB/s, structure-invariant (occ/ILP/VGPR/nt all neutral).
// R7/R8: stream/gather split probes. R8 learned: harness fills stream at
//   6.7 TB/s (so no systemic BW cap) and the split (~3.8M requests) summed
//   to ~68 us. Request-rate accounting unifies ALL results at ~52-56 G
//   requests/s: the kernel is TRANSACTION-bound (divergent 12-20 B reads),
//   not byte-bound.
// R9 (this round): fused + 16 B/face packed table. 9 colors x 14-bit
//   fixed-point in one uint4 -> the color gather is ONE dwordx4, one
//   sector, never straddles (1.3M -> 1.0M requests, no split waste);
//   3.2 MB table fits per-XCD L2. Decode ~30 VALU ops (VALU at 12%).
//   Err 3e-5 vs 0.02 tolerance. Also removes R8's 32 MB record traffic.

#define KFRAG 8

typedef int   ivec4 __attribute__((ext_vector_type(4)));
typedef float fvec4 __attribute__((ext_vector_type(4)));
typedef unsigned int uvec4 __attribute__((ext_vector_type(4)));
typedef float fvec4a __attribute__((ext_vector_type(4), aligned(4)));
typedef unsigned int uvec4a __attribute__((ext_vector_type(4), aligned(4)));

constexpr float SIGMA_INV = 1e4f;
constexpr float GAMMA_INV = 1e4f;
constexpr float EPS    = 1e-10f;
constexpr float ZFAR   = 100.0f;
constexpr float ZSCALE = 1.0f / 99.0f;
constexpr float ZCUT   = -1.2e-3f;   // exp(ZCUT*1e4) < 1e-5: negligible
constexpr float Q14    = 16383.0f;
constexpr float INV14  = 1.0f / 16383.0f;

// ---- prepass: [F][9] f32 -> [F] uint4, 9 x 14-bit fixed point ----
__global__ __launch_bounds__(256) void repack_kernel(
    const float* __restrict__ fc, uvec4* __restrict__ pt, int F)
{
    int f = blockIdx.x * blockDim.x + threadIdx.x;
    if (f >= F) return;
    float c[9];
    __builtin_memcpy(c, fc + (size_t)f * 9, 36);
    unsigned q[9];
#pragma unroll
    for (int i = 0; i < 9; ++i) {
        float x = fminf(fmaxf(c[i], 0.0f), 1.0f);
        q[i] = (unsigned)(x * Q14 + 0.5f);
    }
    uvec4 w;
    w.x = q[0] | (q[1] << 14) | (q[2] << 28);
    w.y = (q[2] >> 4) | (q[3] << 10) | (q[4] << 24);
    w.z = (q[4] >> 8) | (q[5] << 6) | (q[6] << 20);
    w.w = (q[6] >> 12) | (q[7] << 2) | (q[8] << 16);
    pt[f] = w;
}

// decode 9 x 14-bit -> f32 [vert*3 + chan]
__device__ __forceinline__ void dec9(uvec4 w, float* c) {
    unsigned w0 = w.x, w1 = w.y, w2 = w.z, w3 = w.w;
    c[0] = (float)(w0 & 0x3FFFu) * INV14;
    c[1] = (float)((w0 >> 14) & 0x3FFFu) * INV14;
    c[2] = (float)(((w0 >> 28) | (w1 << 4)) & 0x3FFFu) * INV14;
    c[3] = (float)((w1 >> 10) & 0x3FFFu) * INV14;
    c[4] = (float)(((w1 >> 24) | (w2 << 8)) & 0x3FFFu) * INV14;
    c[5] = (float)((w2 >> 6) & 0x3FFFu) * INV14;
    c[6] = (float)(((w2 >> 20) | (w3 << 12)) & 0x3FFFu) * INV14;
    c[7] = (float)((w3 >> 2) & 0x3FFFu) * INV14;
    c[8] = (float)((w3 >> 16) & 0x3FFFu) * INV14;
}

template <int PACKED>
__global__ __launch_bounds__(256) void soft_shader_kernel(
    const int*   __restrict__ p2f,         // [NP, 8]
    const float* __restrict__ bary,        // [NP, 8, 3]
    const float* __restrict__ zbuf,        // [NP, 8]
    const float* __restrict__ dists,       // [NP, 8]
    const float* __restrict__ fc32,        // [F, 9] f32 (fallback path)
    const uvec4* __restrict__ ptab,        // [F] packed (ws) or null
    float*       __restrict__ out,         // [NP, 4]
    int NP)
{
    int p = blockIdx.x * blockDim.x + threadIdx.x;
    if (p >= NP) return;

    // ---- nt coalesced streams (evict-first; protect the packed table) ----
    const ivec4* p2f4 = (const ivec4*)p2f + (size_t)p * 2;
    ivec4 f0 = __builtin_nontemporal_load(p2f4 + 0);
    ivec4 f1 = __builtin_nontemporal_load(p2f4 + 1);
    const fvec4* zb4 = (const fvec4*)zbuf + (size_t)p * 2;
    fvec4 z0 = __builtin_nontemporal_load(zb4 + 0);
    fvec4 z1 = __builtin_nontemporal_load(zb4 + 1);
    const fvec4* dd4 = (const fvec4*)dists + (size_t)p * 2;
    fvec4 d0 = __builtin_nontemporal_load(dd4 + 0);
    fvec4 d1 = __builtin_nontemporal_load(dd4 + 1);

    int   fid[KFRAG] = {f0.x, f0.y, f0.z, f0.w, f1.x, f1.y, f1.z, f1.w};
    float zb_[KFRAG] = {z0.x, z0.y, z0.z, z0.w, z1.x, z1.y, z1.z, z1.w};
    float dd_[KFRAG] = {d0.x, d0.y, d0.z, d0.w, d1.x, d1.y, d1.z, d1.w};

    // winner = first valid (zbuf sorted ascending -> max zinv among valid)
    int fidw = -1, kw = 0;
#pragma unroll
    for (int k = KFRAG - 1; k >= 0; --k)
        if (fid[k] >= 0) { fidw = fid[k]; kw = k; }

    // ---- issue winner's two gathers (bary 16B + table 16B) early ----
    float wb0 = 0.f, wb1 = 0.f, wb2 = 0.f;
    float fcv[9] = {0, 0, 0, 0, 0, 0, 0, 0, 0};
    if (fidw >= 0) {
        // 12 B bary as one dwordx4; clamp the single end-overrun case
        size_t boff = (size_t)p * 24 + kw * 3;
        bool cl = (boff + 4) > (size_t)NP * 24;
        const float* bb = bary + (boff - (cl ? 1 : 0));
        fvec4a q = *(const fvec4a*)bb;
        wb0 = cl ? q.y : q.x;
        wb1 = cl ? q.z : q.y;
        wb2 = cl ? q.w : q.z;

        if (PACKED) {
            dec9(ptab[fidw], fcv);          // ONE dwordx4, never splits
        } else {
            __builtin_memcpy(fcv, fc32 + (size_t)fidw * 9, 36);
        }
    }

    // ---- softmax algebra (overlaps the gather round-trips) ----
    float zinv[KFRAG], prob[KFRAG];
    float zmax = EPS, keep = 1.0f;
#pragma unroll
    for (int k = 0; k < KFRAG; ++k) {
        bool v = (fid[k] >= 0);
        zinv[k] = v ? ((ZFAR - zb_[k]) * ZSCALE) : 0.0f;
        zmax = fmaxf(zmax, zinv[k]);
        prob[k] = v ? (1.0f / (1.0f + __expf(dd_[k] * SIGMA_INV))) : 0.0f;
        keep *= (1.0f - prob[k]);
    }

    // exact denom over ALL fragments (no texel needed)
    float w[KFRAG], wsum = 0.0f;
#pragma unroll
    for (int k = 0; k < KFRAG; ++k) {
        w[k] = prob[k] * __expf((zinv[k] - zmax) * GAMMA_INV);
        wsum += w[k];
    }
    float delta = fmaxf(__expf((EPS - zmax) * GAMMA_INV), EPS);
    float denom = delta + wsum;

    float wwin = 0.0f; // w[kw] via static cascade
#pragma unroll
    for (int k = KFRAG - 1; k >= 0; --k)
        if (fid[k] >= 0) wwin = w[k];

    float r = 0.f, g = 0.f, b = 0.f;
    if (fidw >= 0) {
        float tr = fmaf(wb0, fcv[0], fmaf(wb1, fcv[3], wb2 * fcv[6]));
        float tg = fmaf(wb0, fcv[1], fmaf(wb1, fcv[4], wb2 * fcv[7]));
        float tb = fmaf(wb0, fcv[2], fmaf(wb1, fcv[5], wb2 * fcv[8]));
        r = wwin * tr;
        g = wwin * tg;
        b = wwin * tb;
    }

    // rare extra gate-passers (~1.1%/pixel): execz-skipped bodies
#pragma unroll
    for (int k = 0; k < KFRAG; ++k) {
        if ((fid[k] >= 0) && (k != kw) && (zinv[k] - zmax > ZCUT)) {
            const float* bp = bary + (size_t)p * 24 + k * 3;
            float c0 = bp[0], c1 = bp[1], c2 = bp[2];
            float e[9];
            if (PACKED) {
                dec9(ptab[fid[k]], e);
            } else {
                __builtin_memcpy(e, fc32 + (size_t)fid[k] * 9, 36);
            }
            float tr = fmaf(c0, e[0], fmaf(c1, e[3], c2 * e[6]));
            float tg = fmaf(c0, e[1], fmaf(c1, e[4], c2 * e[7]));
            float tb = fmaf(c0, e[2], fmaf(c1, e[5], c2 * e[8]));
            r = fmaf(w[k], tr, r);
            g = fmaf(w[k], tg, g);
            b = fmaf(w[k], tb, b);
        }
    }

    float inv = 1.0f / denom;
    fvec4 o;
    o.x = (r + delta) * inv; // background (1,1,1): + delta/denom
    o.y = (g + delta) * inv;
    o.z = (b + delta) * inv;
    o.w = keep;
    __builtin_nontemporal_store(o, (fvec4*)out + p);
}

extern "C" void kernel_launch(void* const* d_in, const int* in_sizes, int n_in,
                              void* d_out, int out_size, void* d_ws, size_t ws_size,
                              hipStream_t stream) {
    const int*   p2f         = (const int*)d_in[0];
    const float* bary        = (const float*)d_in[1];
    const float* zbuf        = (const float*)d_in[2];
    const float* dists       = (const float*)d_in[3];
    const float* face_colors = (const float*)d_in[4];
    float* out = (float*)d_out;

    int NP = in_sizes[0] / KFRAG; // N*H*W pixels
    int F  = in_sizes[4] / 9;     // faces
    size_t need = (size_t)F * 16; // 3.2 MB packed table

    int block = 256;
    int grid  = (NP + block - 1) / block;

    if (d_ws && ws_size >= need) {
        uvec4* pt = (uvec4*)d_ws;
        int rgrid = (F + block - 1) / block;
        repack_kernel<<<rgrid, block, 0, stream>>>(face_colors, pt, F);
        soft_shader_kernel<1><<<grid, block, 0, stream>>>(
            p2f, bary, zbuf, dists, face_colors, pt, out, NP);
    } else {
        soft_shader_kernel<0><<<grid, block, 0, stream>>>(
            p2f, bary, zbuf, dists, face_colors, nullptr, out, NP);
    }
}